// Round 4
// baseline (357.936 us; speedup 1.0000x reference)
//
#include <hip/hip_runtime.h>

typedef short s16x8 __attribute__((ext_vector_type(8)));
typedef float f32x4 __attribute__((ext_vector_type(4)));
typedef unsigned int u32x2 __attribute__((ext_vector_type(2)));

__device__ inline float bf2f(unsigned short u) {
    union { float f; unsigned int i; } x; x.i = ((unsigned int)u) << 16; return x.f;
}
__device__ inline unsigned short f2bf(float f) {
    union { float f; unsigned int i; } x; x.f = f;
    unsigned int r = x.i + 0x7fff + ((x.i >> 16) & 1);
    return (unsigned short)(r >> 16);
}
__device__ inline unsigned int cvt_pk_bf16(float lo, float hi) {
    unsigned int r;
    asm("v_cvt_pk_bf16_f32 %0, %1, %2" : "=v"(r) : "v"(lo), "v"(hi));
    return r;
}

__device__ inline void gload_lds16(const unsigned short* g, unsigned short* l) {
    __builtin_amdgcn_global_load_lds(
        (const __attribute__((address_space(1))) unsigned int*)g,
        (__attribute__((address_space(3))) unsigned int*)l, 16, 0, 0);
}

// ---------------------------------------------------------------------------
// Input dtype probe: fp32 low-halves have ~uniform exponent bits; bf16 data
// concentrates in [117,129]. flag=1 -> inputs are fp32.
// ---------------------------------------------------------------------------
__global__ void detect_dtype(const unsigned short* __restrict__ x16, int* flag) {
    __shared__ int s[256];
    int tid = threadIdx.x;
    int cnt = 0;
    for (int i = tid; i < 4096; i += 256) {
        unsigned short u = x16[2 * i];
        int e = (u >> 7) & 0xFF;
        if (e >= 117 && e <= 129) cnt++;
    }
    s[tid] = cnt;
    __syncthreads();
    for (int off = 128; off; off >>= 1) {
        if (tid < off) s[tid] += s[tid + off];
        __syncthreads();
    }
    if (tid == 0) *flag = (s[0] < 2048) ? 1 : 0;
}

__global__ void convert_x(const void* __restrict__ in, unsigned short* __restrict__ out,
                          const int* __restrict__ flag, int n) {
    int mode = *flag;
    int i0 = (blockIdx.x * 256 + threadIdx.x) * 8;
    if (i0 >= n) return;
    if (mode) {
        const float* f = (const float*)in;
#pragma unroll
        for (int j = 0; j < 8; ++j) out[i0 + j] = f2bf(f[i0 + j]);
    } else {
        *(s16x8*)(out + i0) = *(const s16x8*)((const unsigned short*)in + i0);
    }
}

__global__ void cvt_bias(const void* __restrict__ in, float* __restrict__ out,
                         const int* __restrict__ flag, int n) {
    int i = blockIdx.x * 256 + threadIdx.x;
    if (i >= n) return;
    out[i] = (*flag) ? ((const float*)in)[i] : bf2f(((const unsigned short*)in)[i]);
}

// ---------------------------------------------------------------------------
// Transpose + convert weights: (R x C) fp32/bf16 -> (C x R) bf16
// ---------------------------------------------------------------------------
__global__ void transpose_cvt(const void* __restrict__ in, unsigned short* __restrict__ out,
                              const int* __restrict__ flag, int R, int C) {
    __shared__ unsigned short t[64][72];
    int mode = *flag;
    int r0 = blockIdx.y * 64, c0 = blockIdx.x * 64;
    for (int i = threadIdx.x; i < 64 * 64; i += 256) {
        int r = i >> 6, c = i & 63;
        size_t idx = (size_t)(r0 + r) * C + (c0 + c);
        t[r][c] = mode ? f2bf(((const float*)in)[idx]) : ((const unsigned short*)in)[idx];
    }
    __syncthreads();
    for (int i = threadIdx.x; i < 64 * 64; i += 256) {
        int c = i >> 6, r = i & 63;
        out[(size_t)(c0 + c) * R + (r0 + r)] = t[r][c];
    }
}

// ---------------------------------------------------------------------------
// V transpose: qkv V region -> Vt[bh][64 d][2048 k] (bf16)
// ---------------------------------------------------------------------------
__global__ __launch_bounds__(256) void transpose_v(
    const unsigned short* __restrict__ qkv, unsigned short* __restrict__ Vt) {
    __shared__ unsigned short t[64][72];
    int bh = blockIdx.y; int b = bh >> 4, h = bh & 15;
    int k0 = blockIdx.x * 64;
    int tid = threadIdx.x;
    int kr = tid >> 2, db = (tid & 3) * 16;
    const unsigned short* src = qkv + ((size_t)(k0 + kr) * 4 + b) * 3072 + 2048 + h * 64 + db;
    *(s16x8*)&t[kr][db] = *(const s16x8*)src;
    *(s16x8*)&t[kr][db + 8] = *(const s16x8*)(src + 8);
    __syncthreads();
    int d = tid >> 2, kb = (tid & 3) * 16;
    unsigned short* dst = Vt + (size_t)bh * 131072 + (size_t)d * 2048 + k0 + kb;
    s16x8 a, c;
#pragma unroll
    for (int j = 0; j < 8; ++j) a[j] = t[kb + j][d];
#pragma unroll
    for (int j = 0; j < 8; ++j) c[j] = t[kb + 8 + j][d];
    *(s16x8*)dst = a;
    *(s16x8*)(dst + 8) = c;
}

// ---------------------------------------------------------------------------
// GEMM: C = A * BT^T + bias. cols < qcols get *qscale.
// 128x128 tile, BK=64, 4 waves.
// ---------------------------------------------------------------------------
__global__ __launch_bounds__(256) void gemm_bias_kernel(
    const unsigned short* __restrict__ A, const unsigned short* __restrict__ BT,
    const float* __restrict__ bias, void* __restrict__ Cout,
    int M, int N, int K, int qcols, float qscale, const int* __restrict__ outf32flag) {
    __shared__ unsigned short As[8 * 128 * 8];
    __shared__ unsigned short Bs[8 * 128 * 8];
    int tid = threadIdx.x;
    int lane = tid & 63, w = tid >> 6;
    int wr = w >> 1, wc = w & 1;
    int m0 = blockIdx.y * 128, n0 = blockIdx.x * 128;

    f32x4 z = {0.f, 0.f, 0.f, 0.f};
    f32x4 acc[4][4];
#pragma unroll
    for (int m = 0; m < 4; ++m)
#pragma unroll
        for (int n = 0; n < 4; ++n) acc[m][n] = z;

    for (int k0 = 0; k0 < K; k0 += 64) {
        __syncthreads();
#pragma unroll
        for (int i = 0; i < 4; ++i) {
            int c = (w * 4 + i) * 64 + lane;
            int gg = c >> 7, row = c & 127;
            gload_lds16(A + (size_t)(m0 + row) * K + (k0 + gg * 8),
                        As + (size_t)(w * 4 + i) * 512);
            gload_lds16(BT + (size_t)(n0 + row) * K + (k0 + gg * 8),
                        Bs + (size_t)(w * 4 + i) * 512);
        }
        __syncthreads();
#pragma unroll
        for (int kk = 0; kk < 2; ++kk) {
            int gg = kk * 4 + (lane >> 4);
            s16x8 af[4], bf[4];
#pragma unroll
            for (int m = 0; m < 4; ++m)
                af[m] = *(const s16x8*)(As + ((size_t)gg * 128 + wr * 64 + m * 16 + (lane & 15)) * 8);
#pragma unroll
            for (int n = 0; n < 4; ++n)
                bf[n] = *(const s16x8*)(Bs + ((size_t)gg * 128 + wc * 64 + n * 16 + (lane & 15)) * 8);
#pragma unroll
            for (int m = 0; m < 4; ++m)
#pragma unroll
                for (int n = 0; n < 4; ++n)
                    acc[m][n] = __builtin_amdgcn_mfma_f32_16x16x32_bf16(af[m], bf[n], acc[m][n], 0, 0, 0);
        }
    }

    bool f32out = (outf32flag != nullptr) && (*outf32flag != 0);
    int crow0 = m0 + wr * 64;
    int ccol0 = n0 + wc * 64;
#pragma unroll
    for (int n = 0; n < 4; ++n) {
        int col = ccol0 + n * 16 + (lane & 15);
        float bv = bias[col];
        float qs = (col < qcols) ? qscale : 1.0f;
#pragma unroll
        for (int m = 0; m < 4; ++m) {
            int rbase = crow0 + m * 16 + (lane >> 4) * 4;
#pragma unroll
            for (int q = 0; q < 4; ++q) {
                float v = (acc[m][n][q] + bv) * qs;
                if (f32out)
                    ((float*)Cout)[(size_t)(rbase + q) * N + col] = v;
                else
                    ((unsigned short*)Cout)[(size_t)(rbase + q) * N + col] = f2bf(v);
            }
        }
    }
}

// ---------------------------------------------------------------------------
// Flash attention, swapped operands, exp2 domain (Q prescaled by 0.125*log2e).
// Block: one (b,h), 128 q-rows = 4 waves x 2 subtiles x 16. KV tiles of 64.
// Double-buffered K/V staging with counted vmcnt (loads fly under compute).
// ---------------------------------------------------------------------------
__global__ __launch_bounds__(256) void attn_kernel(
    const unsigned short* __restrict__ qkv, const unsigned short* __restrict__ Vt,
    unsigned short* __restrict__ O) {
    int bh = blockIdx.y;
    int b = bh >> 4, h = bh & 15;
    int q0 = blockIdx.x * 128;
    int tid = threadIdx.x, lane = tid & 63, w = tid >> 6;
    int g = lane >> 4, qh = lane & 15;

    __shared__ unsigned short Ks[2][8 * 64 * 8];   // 16KB
    __shared__ unsigned short Vs[2][64 * 64];      // 16KB
    __shared__ unsigned short Pb[4][2][16 * 64];   // 16KB

    // Q fragments (prescaled)
    s16x8 qf[2][2];
#pragma unroll
    for (int qs = 0; qs < 2; ++qs) {
        int qrow = q0 + w * 32 + qs * 16 + qh;
        const unsigned short* qp = qkv + ((size_t)qrow * 4 + b) * 3072 + h * 64 + g * 8;
        qf[qs][0] = *(const s16x8*)qp;
        qf[qs][1] = *(const s16x8*)(qp + 32);
    }
    // Drain Q loads so vmcnt counts only staging DMAs below.
    asm volatile("s_waitcnt vmcnt(0)" ::: "memory");

    f32x4 z = {0.f, 0.f, 0.f, 0.f};
    f32x4 oacc[2][4];
#pragma unroll
    for (int qs = 0; qs < 2; ++qs)
#pragma unroll
        for (int dt = 0; dt < 4; ++dt) oacc[qs][dt] = z;
    float mrun[2] = {-1e30f, -1e30f};
    float lrun[2] = {0.f, 0.f};

    int vxor = (lane & 7) ^ (lane >> 3);

    // 4 global_load_lds per wave per tile (2 K + 2 V)
    auto stage = [&](int buf, int t) {
        int kk0 = t * 64;
        const unsigned short* ksrc = qkv + ((size_t)(kk0 + lane) * 4 + b) * 3072 + 1024 + h * 64;
        gload_lds16(ksrc + w * 8, &Ks[buf][0] + (size_t)w * 512);
        gload_lds16(ksrc + (w + 4) * 8, &Ks[buf][0] + (size_t)(w + 4) * 512);
#pragma unroll
        for (int c = 0; c < 2; ++c) {
            int d = (c * 4 + w) * 8 + (lane >> 3);
            const unsigned short* vsrc = Vt + (size_t)bh * 131072 + (size_t)d * 2048 + kk0 + vxor * 8;
            gload_lds16(vsrc, &Vs[buf][0] + (size_t)(c * 4 + w) * 512);
        }
    };

    stage(0, 0);
    for (int t = 0; t < 32; ++t) {
        int cur = t & 1;
        // all waves done reading buf cur^1 (tile t-1) -> safe to overwrite
        __builtin_amdgcn_s_barrier();
        if (t + 1 < 32) {
            stage(cur ^ 1, t + 1);
            asm volatile("s_waitcnt vmcnt(4)" ::: "memory");  // cur's 4 done, next's in flight
        } else {
            asm volatile("s_waitcnt vmcnt(0)" ::: "memory");
        }
        __builtin_amdgcn_s_barrier();  // everyone's cur tile staged

        // ---- S^T[k][q] = K Q^T (log2 domain)
        f32x4 sc[2][4];
#pragma unroll
        for (int qs = 0; qs < 2; ++qs)
#pragma unroll
            for (int ct = 0; ct < 4; ++ct) sc[qs][ct] = z;
#pragma unroll
        for (int kk = 0; kk < 2; ++kk)
#pragma unroll
            for (int ct = 0; ct < 4; ++ct) {
                s16x8 kf = *(const s16x8*)(&Ks[cur][0] + ((size_t)(kk * 4 + g) * 64 + ct * 16 + qh) * 8);
                sc[0][ct] = __builtin_amdgcn_mfma_f32_16x16x32_bf16(kf, qf[0][kk], sc[0][ct], 0, 0, 0);
                sc[1][ct] = __builtin_amdgcn_mfma_f32_16x16x32_bf16(kf, qf[1][kk], sc[1][ct], 0, 0, 0);
            }

        // ---- online softmax, defer-max (THR=8 in log2 domain)
#pragma unroll
        for (int qs = 0; qs < 2; ++qs) {
            float tmax = sc[qs][0][0];
#pragma unroll
            for (int ct = 0; ct < 4; ++ct)
#pragma unroll
                for (int r = 0; r < 4; ++r) tmax = fmaxf(tmax, sc[qs][ct][r]);
            tmax = fmaxf(tmax, __shfl_xor(tmax, 16));
            tmax = fmaxf(tmax, __shfl_xor(tmax, 32));
            if (__any(tmax > mrun[qs] + 8.f)) {
                float mnew = fmaxf(mrun[qs], tmax);
                float alpha = exp2f(mrun[qs] - mnew);
                mrun[qs] = mnew;
                lrun[qs] *= alpha;
#pragma unroll
                for (int dt = 0; dt < 4; ++dt) oacc[qs][dt] *= alpha;
            }
            float m = mrun[qs];
            float rsum = 0.f;
            unsigned short* pwq = &Pb[w][qs][0];
#pragma unroll
            for (int ct = 0; ct < 4; ++ct) {
                float p0 = exp2f(sc[qs][ct][0] - m);
                float p1 = exp2f(sc[qs][ct][1] - m);
                float p2 = exp2f(sc[qs][ct][2] - m);
                float p3 = exp2f(sc[qs][ct][3] - m);
                rsum += (p0 + p1) + (p2 + p3);
                u32x2 pv;
                pv[0] = cvt_pk_bf16(p0, p1);
                pv[1] = cvt_pk_bf16(p2, p3);
                int blk = ct * 2 + (g >> 1);
                int e = qh * 64 + ((blk ^ (qh & 7)) * 8) + (g & 1) * 4;
                *(u32x2*)(pwq + e) = pv;
            }
            rsum += __shfl_xor(rsum, 16);
            rsum += __shfl_xor(rsum, 32);
            lrun[qs] += rsum;
        }

        // P writes must complete before B-frag reads (same wave, cross-lane)
        asm volatile("s_waitcnt lgkmcnt(0)" ::: "memory");
        __builtin_amdgcn_sched_barrier(0);

        // ---- O^T += V^T P
#pragma unroll
        for (int kk2 = 0; kk2 < 2; ++kk2) {
            int blkr = ((kk2 * 4 + g) ^ (qh & 7)) * 8;
            s16x8 pb0 = *(const s16x8*)(&Pb[w][0][0] + qh * 64 + blkr);
            s16x8 pb1 = *(const s16x8*)(&Pb[w][1][0] + qh * 64 + blkr);
#pragma unroll
            for (int dt = 0; dt < 4; ++dt) {
                s16x8 vtf = *(const s16x8*)(&Vs[cur][0] + (size_t)(dt * 16 + qh) * 64 + blkr);
                oacc[0][dt] = __builtin_amdgcn_mfma_f32_16x16x32_bf16(vtf, pb0, oacc[0][dt], 0, 0, 0);
                oacc[1][dt] = __builtin_amdgcn_mfma_f32_16x16x32_bf16(vtf, pb1, oacc[1][dt], 0, 0, 0);
            }
        }
    }

    // ---- epilogue
#pragma unroll
    for (int qs = 0; qs < 2; ++qs) {
        float rl = 1.f / lrun[qs];
        int s = q0 + w * 32 + qs * 16 + qh;
        unsigned short* orow = O + ((size_t)s * 4 + b) * 1024 + h * 64;
#pragma unroll
        for (int dt = 0; dt < 4; ++dt) {
            u32x2 pv;
            pv[0] = cvt_pk_bf16(oacc[qs][dt][0] * rl, oacc[qs][dt][1] * rl);
            pv[1] = cvt_pk_bf16(oacc[qs][dt][2] * rl, oacc[qs][dt][3] * rl);
            *(u32x2*)(orow + dt * 16 + g * 4) = pv;
        }
    }
}

// ---------------------------------------------------------------------------
extern "C" void kernel_launch(void* const* d_in, const int* in_sizes, int n_in,
                              void* d_out, int out_size, void* d_ws, size_t ws_size,
                              hipStream_t stream) {
    const void* x    = d_in[0];
    const void* Wqkv = d_in[1];
    const void* bqkv = d_in[2];
    const void* Wout = d_in[3];
    const void* bout = d_in[4];

    char* ws = (char*)d_ws;
    unsigned short* qkv   = (unsigned short*)(ws);              // 48MB
    unsigned short* Obuf  = (unsigned short*)(ws + 50331648);   // 16MB
    unsigned short* WqkvT = (unsigned short*)(ws + 67108864);   // 6MB
    unsigned short* WoutT = (unsigned short*)(ws + 73400320);   // 2MB
    unsigned short* xb    = (unsigned short*)(ws + 75497472);   // 16MB (reused as Vt)
    unsigned short* Vtg   = xb;                                 // alias: xb dead after GEMM1
    float*          bq_f  = (float*)(ws + 92274688);
    float*          bo_f  = (float*)(ws + 92286976);
    int*            flag  = (int*)(ws + 92291072);

    detect_dtype<<<1, 256, 0, stream>>>((const unsigned short*)x, flag);
    convert_x<<<4096, 256, 0, stream>>>(x, xb, flag, 8388608);
    cvt_bias<<<12, 256, 0, stream>>>(bqkv, bq_f, flag, 3072);
    cvt_bias<<<4, 256, 0, stream>>>(bout, bo_f, flag, 1024);
    transpose_cvt<<<dim3(48, 16), 256, 0, stream>>>(Wqkv, WqkvT, flag, 1024, 3072);
    transpose_cvt<<<dim3(16, 16), 256, 0, stream>>>(Wout, WoutT, flag, 1024, 1024);

    // Q prescale = 0.125 * log2(e) -> softmax computed in exp2 domain
    gemm_bias_kernel<<<dim3(24, 64), 256, 0, stream>>>(xb, WqkvT, bq_f, qkv,
                                                       8192, 3072, 1024, 1024, 0.18033688f, nullptr);
    transpose_v<<<dim3(32, 64), 256, 0, stream>>>(qkv, Vtg);
    attn_kernel<<<dim3(16, 64), 256, 0, stream>>>(qkv, Vtg, Obuf);
    gemm_bias_kernel<<<dim3(8, 64), 256, 0, stream>>>(Obuf, WoutT, bo_f, d_out,
                                                      8192, 1024, 1024, 0, 1.0f, flag);
}

// Round 5
// 357.922 us; speedup vs baseline: 1.0000x; 1.0000x over previous
//
#include <hip/hip_runtime.h>

typedef short s16x8 __attribute__((ext_vector_type(8)));
typedef float f32x4 __attribute__((ext_vector_type(4)));
typedef unsigned int u32x2 __attribute__((ext_vector_type(2)));

__device__ inline float bf2f(unsigned short u) {
    union { float f; unsigned int i; } x; x.i = ((unsigned int)u) << 16; return x.f;
}
__device__ inline unsigned short f2bf(float f) {
    union { float f; unsigned int i; } x; x.f = f;
    unsigned int r = x.i + 0x7fff + ((x.i >> 16) & 1);
    return (unsigned short)(r >> 16);
}
__device__ inline unsigned int cvt_pk_bf16(float lo, float hi) {
    unsigned int r;
    asm("v_cvt_pk_bf16_f32 %0, %1, %2" : "=v"(r) : "v"(lo), "v"(hi));
    return r;
}

__device__ inline void gload_lds16(const unsigned short* g, unsigned short* l) {
    __builtin_amdgcn_global_load_lds(
        (const __attribute__((address_space(1))) unsigned int*)g,
        (__attribute__((address_space(3))) unsigned int*)l, 16, 0, 0);
}

// ---------------------------------------------------------------------------
// Input dtype probe: fp32 low-halves have ~uniform exponent bits; bf16 data
// concentrates in [117,129]. flag=1 -> inputs are fp32.
// ---------------------------------------------------------------------------
__global__ void detect_dtype(const unsigned short* __restrict__ x16, int* flag) {
    __shared__ int s[256];
    int tid = threadIdx.x;
    int cnt = 0;
    for (int i = tid; i < 4096; i += 256) {
        unsigned short u = x16[2 * i];
        int e = (u >> 7) & 0xFF;
        if (e >= 117 && e <= 129) cnt++;
    }
    s[tid] = cnt;
    __syncthreads();
    for (int off = 128; off; off >>= 1) {
        if (tid < off) s[tid] += s[tid + off];
        __syncthreads();
    }
    if (tid == 0) *flag = (s[0] < 2048) ? 1 : 0;
}

__global__ void convert_x(const void* __restrict__ in, unsigned short* __restrict__ out,
                          const int* __restrict__ flag, int n) {
    int mode = *flag;
    int i0 = (blockIdx.x * 256 + threadIdx.x) * 8;
    if (i0 >= n) return;
    if (mode) {
        const float* f = (const float*)in;
#pragma unroll
        for (int j = 0; j < 8; ++j) out[i0 + j] = f2bf(f[i0 + j]);
    } else {
        *(s16x8*)(out + i0) = *(const s16x8*)((const unsigned short*)in + i0);
    }
}

__global__ void cvt_bias(const void* __restrict__ in, float* __restrict__ out,
                         const int* __restrict__ flag, int n) {
    int i = blockIdx.x * 256 + threadIdx.x;
    if (i >= n) return;
    out[i] = (*flag) ? ((const float*)in)[i] : bf2f(((const unsigned short*)in)[i]);
}

// ---------------------------------------------------------------------------
// Transpose + convert weights: (R x C) fp32/bf16 -> (C x R) bf16
// ---------------------------------------------------------------------------
__global__ void transpose_cvt(const void* __restrict__ in, unsigned short* __restrict__ out,
                              const int* __restrict__ flag, int R, int C) {
    __shared__ unsigned short t[64][72];
    int mode = *flag;
    int r0 = blockIdx.y * 64, c0 = blockIdx.x * 64;
    for (int i = threadIdx.x; i < 64 * 64; i += 256) {
        int r = i >> 6, c = i & 63;
        size_t idx = (size_t)(r0 + r) * C + (c0 + c);
        t[r][c] = mode ? f2bf(((const float*)in)[idx]) : ((const unsigned short*)in)[idx];
    }
    __syncthreads();
    for (int i = threadIdx.x; i < 64 * 64; i += 256) {
        int c = i >> 6, r = i & 63;
        out[(size_t)(c0 + c) * R + (r0 + r)] = t[r][c];
    }
}

// ---------------------------------------------------------------------------
// V transpose: qkv V region -> Vt[bh][64 d][2048 k] (bf16)
// ---------------------------------------------------------------------------
__global__ __launch_bounds__(256) void transpose_v(
    const unsigned short* __restrict__ qkv, unsigned short* __restrict__ Vt) {
    __shared__ unsigned short t[64][72];
    int bh = blockIdx.y; int b = bh >> 4, h = bh & 15;
    int k0 = blockIdx.x * 64;
    int tid = threadIdx.x;
    int kr = tid >> 2, db = (tid & 3) * 16;
    const unsigned short* src = qkv + ((size_t)(k0 + kr) * 4 + b) * 3072 + 2048 + h * 64 + db;
    *(s16x8*)&t[kr][db] = *(const s16x8*)src;
    *(s16x8*)&t[kr][db + 8] = *(const s16x8*)(src + 8);
    __syncthreads();
    int d = tid >> 2, kb = (tid & 3) * 16;
    unsigned short* dst = Vt + (size_t)bh * 131072 + (size_t)d * 2048 + k0 + kb;
    s16x8 a, c;
#pragma unroll
    for (int j = 0; j < 8; ++j) a[j] = t[kb + j][d];
#pragma unroll
    for (int j = 0; j < 8; ++j) c[j] = t[kb + 8 + j][d];
    *(s16x8*)dst = a;
    *(s16x8*)(dst + 8) = c;
}

// ---------------------------------------------------------------------------
// GEMM: C = A * BT^T + bias. cols < qcols get *qscale.
// 128x128 tile, BK=64, 4 waves, double-buffered LDS with 2-phase pipeline
// (T3-minimum: issue next tile's global_load_lds BEFORE current compute;
// one vmcnt(0)+barrier per K-step).
// ---------------------------------------------------------------------------
__global__ __launch_bounds__(256) void gemm_bias_kernel(
    const unsigned short* __restrict__ A, const unsigned short* __restrict__ BT,
    const float* __restrict__ bias, void* __restrict__ Cout,
    int M, int N, int K, int qcols, float qscale, const int* __restrict__ outf32flag) {
    __shared__ unsigned short As[2][8 * 128 * 8];  // 32KB
    __shared__ unsigned short Bs[2][8 * 128 * 8];  // 32KB
    int tid = threadIdx.x;
    int lane = tid & 63, w = tid >> 6;
    int wr = w >> 1, wc = w & 1;
    int m0 = blockIdx.y * 128, n0 = blockIdx.x * 128;

    f32x4 z = {0.f, 0.f, 0.f, 0.f};
    f32x4 acc[4][4];
#pragma unroll
    for (int m = 0; m < 4; ++m)
#pragma unroll
        for (int n = 0; n < 4; ++n) acc[m][n] = z;

    auto stage = [&](int buf, int k0) {
#pragma unroll
        for (int i = 0; i < 4; ++i) {
            int c = (w * 4 + i) * 64 + lane;
            int gg = c >> 7, row = c & 127;
            gload_lds16(A + (size_t)(m0 + row) * K + (k0 + gg * 8),
                        &As[buf][0] + (size_t)(w * 4 + i) * 512);
            gload_lds16(BT + (size_t)(n0 + row) * K + (k0 + gg * 8),
                        &Bs[buf][0] + (size_t)(w * 4 + i) * 512);
        }
    };

    int nt = K >> 6;
    stage(0, 0);
    asm volatile("s_waitcnt vmcnt(0)" ::: "memory");
    __builtin_amdgcn_s_barrier();

    for (int t = 0; t < nt; ++t) {
        int cur = t & 1;
        if (t + 1 < nt) stage(cur ^ 1, (t + 1) * 64);   // loads fly under compute
        const unsigned short* Ab = &As[cur][0];
        const unsigned short* Bb = &Bs[cur][0];
#pragma unroll
        for (int kk = 0; kk < 2; ++kk) {
            int gg = kk * 4 + (lane >> 4);
            s16x8 af[4], bf[4];
#pragma unroll
            for (int m = 0; m < 4; ++m)
                af[m] = *(const s16x8*)(Ab + ((size_t)gg * 128 + wr * 64 + m * 16 + (lane & 15)) * 8);
#pragma unroll
            for (int n = 0; n < 4; ++n)
                bf[n] = *(const s16x8*)(Bb + ((size_t)gg * 128 + wc * 64 + n * 16 + (lane & 15)) * 8);
            __builtin_amdgcn_s_setprio(1);
#pragma unroll
            for (int m = 0; m < 4; ++m)
#pragma unroll
                for (int n = 0; n < 4; ++n)
                    acc[m][n] = __builtin_amdgcn_mfma_f32_16x16x32_bf16(af[m], bf[n], acc[m][n], 0, 0, 0);
            __builtin_amdgcn_s_setprio(0);
        }
        asm volatile("s_waitcnt vmcnt(0)" ::: "memory");  // next tile staged
        __builtin_amdgcn_s_barrier();                     // all waves done with cur
    }

    bool f32out = (outf32flag != nullptr) && (*outf32flag != 0);
    int crow0 = m0 + wr * 64;
    int ccol0 = n0 + wc * 64;
#pragma unroll
    for (int n = 0; n < 4; ++n) {
        int col = ccol0 + n * 16 + (lane & 15);
        float bv = bias[col];
        float qs = (col < qcols) ? qscale : 1.0f;
#pragma unroll
        for (int m = 0; m < 4; ++m) {
            int rbase = crow0 + m * 16 + (lane >> 4) * 4;
#pragma unroll
            for (int q = 0; q < 4; ++q) {
                float v = (acc[m][n][q] + bv) * qs;
                if (f32out)
                    ((float*)Cout)[(size_t)(rbase + q) * N + col] = v;
                else
                    ((unsigned short*)Cout)[(size_t)(rbase + q) * N + col] = f2bf(v);
            }
        }
    }
}

// ---------------------------------------------------------------------------
// Flash attention, swapped operands, exp2 domain (Q prescaled by 0.125*log2e).
// Round-3 sync structure (single K/V buffer, 32KB LDS) + cvt_pk + defer-max
// + setprio around MFMA clusters.
// ---------------------------------------------------------------------------
__global__ __launch_bounds__(256) void attn_kernel(
    const unsigned short* __restrict__ qkv, const unsigned short* __restrict__ Vt,
    unsigned short* __restrict__ O) {
    int bh = blockIdx.y;
    int b = bh >> 4, h = bh & 15;
    int q0 = blockIdx.x * 128;
    int tid = threadIdx.x, lane = tid & 63, w = tid >> 6;
    int g = lane >> 4, qh = lane & 15;

    __shared__ unsigned short Ks[8 * 64 * 8];     // 8KB
    __shared__ unsigned short Vs[64 * 64];        // 8KB
    __shared__ unsigned short Pb[4][2][16 * 64];  // 16KB

    // Q fragments (prescaled by 0.125*log2e in GEMM1 epilogue)
    s16x8 qf[2][2];
#pragma unroll
    for (int qs = 0; qs < 2; ++qs) {
        int qrow = q0 + w * 32 + qs * 16 + qh;
        const unsigned short* qp = qkv + ((size_t)qrow * 4 + b) * 3072 + h * 64 + g * 8;
        qf[qs][0] = *(const s16x8*)qp;
        qf[qs][1] = *(const s16x8*)(qp + 32);
    }

    f32x4 z = {0.f, 0.f, 0.f, 0.f};
    f32x4 oacc[2][4];
#pragma unroll
    for (int qs = 0; qs < 2; ++qs)
#pragma unroll
        for (int dt = 0; dt < 4; ++dt) oacc[qs][dt] = z;
    float mrun[2] = {-1e30f, -1e30f};
    float lrun[2] = {0.f, 0.f};

    int vxor = (lane & 7) ^ (lane >> 3);

    for (int k0 = 0; k0 < 2048; k0 += 64) {
        __syncthreads();
        // stage K tile: Ks[gd][k][e] = K[k0+k][gd*8+e]
        {
            const unsigned short* ksrc = qkv + ((size_t)(k0 + lane) * 4 + b) * 3072 + 1024 + h * 64;
            gload_lds16(ksrc + w * 8, Ks + (size_t)w * 512);
            gload_lds16(ksrc + (w + 4) * 8, Ks + (size_t)(w + 4) * 512);
        }
        // stage V^T tile, inverse-swizzled source, linear LDS dest
#pragma unroll
        for (int c = 0; c < 2; ++c) {
            int d = (c * 4 + w) * 8 + (lane >> 3);
            const unsigned short* vsrc = Vt + (size_t)bh * 131072 + (size_t)d * 2048 + k0 + vxor * 8;
            gload_lds16(vsrc, Vs + (size_t)(c * 4 + w) * 512);
        }
        __syncthreads();

        // ---- S^T[k][q] = K Q^T (log2 domain)
        f32x4 sc[2][4];
#pragma unroll
        for (int qs = 0; qs < 2; ++qs)
#pragma unroll
            for (int ct = 0; ct < 4; ++ct) sc[qs][ct] = z;
        __builtin_amdgcn_s_setprio(1);
#pragma unroll
        for (int kk = 0; kk < 2; ++kk)
#pragma unroll
            for (int ct = 0; ct < 4; ++ct) {
                s16x8 kf = *(const s16x8*)(Ks + ((size_t)(kk * 4 + g) * 64 + ct * 16 + qh) * 8);
                sc[0][ct] = __builtin_amdgcn_mfma_f32_16x16x32_bf16(kf, qf[0][kk], sc[0][ct], 0, 0, 0);
                sc[1][ct] = __builtin_amdgcn_mfma_f32_16x16x32_bf16(kf, qf[1][kk], sc[1][ct], 0, 0, 0);
            }
        __builtin_amdgcn_s_setprio(0);

        // ---- online softmax, defer-max (THR=8 in log2 domain)
#pragma unroll
        for (int qs = 0; qs < 2; ++qs) {
            float tmax = sc[qs][0][0];
#pragma unroll
            for (int ct = 0; ct < 4; ++ct)
#pragma unroll
                for (int r = 0; r < 4; ++r) tmax = fmaxf(tmax, sc[qs][ct][r]);
            tmax = fmaxf(tmax, __shfl_xor(tmax, 16));
            tmax = fmaxf(tmax, __shfl_xor(tmax, 32));
            if (__any(tmax > mrun[qs] + 8.f)) {
                float mnew = fmaxf(mrun[qs], tmax);
                float alpha = exp2f(mrun[qs] - mnew);
                mrun[qs] = mnew;
                lrun[qs] *= alpha;
#pragma unroll
                for (int dt = 0; dt < 4; ++dt) oacc[qs][dt] *= alpha;
            }
            float m = mrun[qs];
            float rsum = 0.f;
            unsigned short* pwq = &Pb[w][qs][0];
#pragma unroll
            for (int ct = 0; ct < 4; ++ct) {
                float p0 = exp2f(sc[qs][ct][0] - m);
                float p1 = exp2f(sc[qs][ct][1] - m);
                float p2 = exp2f(sc[qs][ct][2] - m);
                float p3 = exp2f(sc[qs][ct][3] - m);
                rsum += (p0 + p1) + (p2 + p3);
                u32x2 pv;
                pv[0] = cvt_pk_bf16(p0, p1);
                pv[1] = cvt_pk_bf16(p2, p3);
                int blk = ct * 2 + (g >> 1);
                int e = qh * 64 + ((blk ^ (qh & 7)) * 8) + (g & 1) * 4;
                *(u32x2*)(pwq + e) = pv;
            }
            rsum += __shfl_xor(rsum, 16);
            rsum += __shfl_xor(rsum, 32);
            lrun[qs] += rsum;
        }

        // P writes must complete before B-frag reads (same wave, cross-lane)
        asm volatile("s_waitcnt lgkmcnt(0)" ::: "memory");
        __builtin_amdgcn_sched_barrier(0);

        // ---- O^T += V^T P
#pragma unroll
        for (int kk2 = 0; kk2 < 2; ++kk2) {
            int blkr = ((kk2 * 4 + g) ^ (qh & 7)) * 8;
            s16x8 pb0 = *(const s16x8*)(&Pb[w][0][0] + qh * 64 + blkr);
            s16x8 pb1 = *(const s16x8*)(&Pb[w][1][0] + qh * 64 + blkr);
            __builtin_amdgcn_s_setprio(1);
#pragma unroll
            for (int dt = 0; dt < 4; ++dt) {
                s16x8 vtf = *(const s16x8*)(Vs + (size_t)(dt * 16 + qh) * 64 + blkr);
                oacc[0][dt] = __builtin_amdgcn_mfma_f32_16x16x32_bf16(vtf, pb0, oacc[0][dt], 0, 0, 0);
                oacc[1][dt] = __builtin_amdgcn_mfma_f32_16x16x32_bf16(vtf, pb1, oacc[1][dt], 0, 0, 0);
            }
            __builtin_amdgcn_s_setprio(0);
        }
    }

    // ---- epilogue
#pragma unroll
    for (int qs = 0; qs < 2; ++qs) {
        float rl = 1.f / lrun[qs];
        int s = q0 + w * 32 + qs * 16 + qh;
        unsigned short* orow = O + ((size_t)s * 4 + b) * 1024 + h * 64;
#pragma unroll
        for (int dt = 0; dt < 4; ++dt) {
            u32x2 pv;
            pv[0] = cvt_pk_bf16(oacc[qs][dt][0] * rl, oacc[qs][dt][1] * rl);
            pv[1] = cvt_pk_bf16(oacc[qs][dt][2] * rl, oacc[qs][dt][3] * rl);
            *(u32x2*)(orow + dt * 16 + g * 4) = pv;
        }
    }
}

// ---------------------------------------------------------------------------
extern "C" void kernel_launch(void* const* d_in, const int* in_sizes, int n_in,
                              void* d_out, int out_size, void* d_ws, size_t ws_size,
                              hipStream_t stream) {
    const void* x    = d_in[0];
    const void* Wqkv = d_in[1];
    const void* bqkv = d_in[2];
    const void* Wout = d_in[3];
    const void* bout = d_in[4];

    char* ws = (char*)d_ws;
    unsigned short* qkv   = (unsigned short*)(ws);              // 48MB
    unsigned short* Obuf  = (unsigned short*)(ws + 50331648);   // 16MB
    unsigned short* WqkvT = (unsigned short*)(ws + 67108864);   // 6MB
    unsigned short* WoutT = (unsigned short*)(ws + 73400320);   // 2MB
    unsigned short* xb    = (unsigned short*)(ws + 75497472);   // 16MB (reused as Vt)
    unsigned short* Vtg   = xb;                                 // alias: xb dead after GEMM1
    float*          bq_f  = (float*)(ws + 92274688);
    float*          bo_f  = (float*)(ws + 92286976);
    int*            flag  = (int*)(ws + 92291072);

    detect_dtype<<<1, 256, 0, stream>>>((const unsigned short*)x, flag);
    convert_x<<<4096, 256, 0, stream>>>(x, xb, flag, 8388608);
    cvt_bias<<<12, 256, 0, stream>>>(bqkv, bq_f, flag, 3072);
    cvt_bias<<<4, 256, 0, stream>>>(bout, bo_f, flag, 1024);
    transpose_cvt<<<dim3(48, 16), 256, 0, stream>>>(Wqkv, WqkvT, flag, 1024, 3072);
    transpose_cvt<<<dim3(16, 16), 256, 0, stream>>>(Wout, WoutT, flag, 1024, 1024);

    // Q prescale = 0.125 * log2(e) -> softmax computed in exp2 domain
    gemm_bias_kernel<<<dim3(24, 64), 256, 0, stream>>>(xb, WqkvT, bq_f, qkv,
                                                       8192, 3072, 1024, 1024, 0.18033688f, nullptr);
    transpose_v<<<dim3(32, 64), 256, 0, stream>>>(qkv, Vtg);
    attn_kernel<<<dim3(16, 64), 256, 0, stream>>>(qkv, Vtg, Obuf);
    gemm_bias_kernel<<<dim3(8, 64), 256, 0, stream>>>(Obuf, WoutT, bo_f, d_out,
                                                      8192, 1024, 1024, 0, 1.0f, flag);
}